// Round 3
// baseline (736.346 us; speedup 1.0000x reference)
//
#include <hip/hip_runtime.h>
#include <math.h>

#define NN   128
#define SS   129          // LDS row stride in float2 (ODD -> conflict-free lane stride)
#define TT   1024         // threads per block for FFT kernels
#define NPIX 16384        // 128*128
#define EPT  16           // NPIX / TT

#if TT != 1024
#error "fft2d unit mapping assumes TT==1024"
#endif

// ---------- register FFTs (radix-2 DIF + final bit-reversal -> natural order) ----------
template<int SGN>
__device__ __forceinline__ void fft8(float2* f) {
    const float R = 0.70710678118654752f;
    const float WC[4] = {1.f, R, 0.f, -R};
    const float WS[4] = {0.f, R, 1.f, R};   // sin(2*pi*t/8)
    #pragma unroll
    for (int stage = 0; stage < 3; ++stage) {
        const int L = 8 >> stage, half = L >> 1, step = 1 << stage;
        #pragma unroll
        for (int base = 0; base < 8; base += L) {
            #pragma unroll
            for (int j = 0; j < half; ++j) {
                float2 u = f[base + j], v = f[base + half + j];
                f[base + j] = make_float2(u.x + v.x, u.y + v.y);
                float dx = u.x - v.x, dy = u.y - v.y;
                const int t = j * step;
                const float wr = WC[t];
                const float wi = (SGN > 0) ? WS[t] : -WS[t];
                f[base + half + j] = make_float2(dx * wr - dy * wi, dx * wi + dy * wr);
            }
        }
    }
    float2 tmp;
    tmp = f[1]; f[1] = f[4]; f[4] = tmp;
    tmp = f[3]; f[3] = f[6]; f[6] = tmp;
}

template<int SGN>
__device__ __forceinline__ void fft16(float2* f) {
    const float WC[8] = {1.f, 0.92387953251f, 0.70710678119f, 0.38268343236f,
                         0.f, -0.38268343236f, -0.70710678119f, -0.92387953251f};
    const float WS[8] = {0.f, 0.38268343236f, 0.70710678119f, 0.92387953251f,
                         1.f, 0.92387953251f, 0.70710678119f, 0.38268343236f};
    #pragma unroll
    for (int stage = 0; stage < 4; ++stage) {
        const int L = 16 >> stage, half = L >> 1, step = 1 << stage;
        #pragma unroll
        for (int base = 0; base < 16; base += L) {
            #pragma unroll
            for (int j = 0; j < half; ++j) {
                float2 u = f[base + j], v = f[base + half + j];
                f[base + j] = make_float2(u.x + v.x, u.y + v.y);
                float dx = u.x - v.x, dy = u.y - v.y;
                const int t = j * step;
                const float wr = WC[t];
                const float wi = (SGN > 0) ? WS[t] : -WS[t];
                f[base + half + j] = make_float2(dx * wr - dy * wi, dx * wi + dy * wr);
            }
        }
    }
    float2 tmp;
    tmp = f[1];  f[1]  = f[8];  f[8]  = tmp;
    tmp = f[2];  f[2]  = f[4];  f[4]  = tmp;
    tmp = f[3];  f[3]  = f[12]; f[12] = tmp;
    tmp = f[5];  f[5]  = f[10]; f[10] = tmp;
    tmp = f[7];  f[7]  = f[14]; f[14] = tmp;
    tmp = f[11]; f[11] = f[13]; f[13] = tmp;
}

// ---------- in-LDS 2D FFT, 128x128 ----------
// Frequency storage is BIT-PERMUTED along each axis: freq k = ka + 8*kb (ka<8, kb<16)
// lives at position p = 16*ka + kb.  psi / ihat are generated in the same layout.
// SGN=-1: forward (natural spatial in -> permuted freq out), unnormalized DFT.
// SGN=+1: inverse (permuted freq in -> natural spatial out), unnormalized (x16384).
// Residue-class-preserving writes make each sweep hazard-free (units touch only their
// own column class), so only 4 barriers per 2D FFT.  Lanes always vary the line index
// (row pass: lane stride SS=129 (odd); col pass: lane stride 1) -> all LDS accesses at
// the wave64 structural minimum of 4 lanes per bank-pair.
template<int SGN>
__device__ void fft2d(float2* __restrict__ F, const float2* __restrict__ tw, int tid) {
    #pragma unroll
    for (int pass = 0; pass < 2; ++pass) {
        const int ES = (pass == 0) ? 1 : SS;   // within-line element stride
        const int LS = (pass == 0) ? SS : 1;   // line stride
        if (SGN < 0) {
            // ---- step A: FFT8 over n1 per residue class t (16 classes x 128 lines) ----
            #pragma unroll
            for (int i = 0; i < 2; ++i) {
                int u = i * TT + tid;
                int t = u >> 7, x = u & 127;
                float2* M = F + x * LS;
                float2 f[8];
                #pragma unroll
                for (int n1 = 0; n1 < 8; ++n1) f[n1] = M[(t + 16 * n1) * ES];
                fft8<-1>(f);
                #pragma unroll
                for (int ka = 0; ka < 8; ++ka) {
                    float2 w = tw[t * ka];          // e^{+2pi i t ka/128}; forward uses conj
                    float2 z = f[ka];
                    M[(t + 16 * ka) * ES] =
                        make_float2(z.x * w.x + z.y * w.y, z.y * w.x - z.x * w.y);
                }
            }
            __syncthreads();
            // ---- step B: FFT16 over t per block ka (8 classes x 128 lines) ----
            {
                int ka = tid >> 7, x = tid & 127;
                float2* M = F + x * LS;
                float2 g[16];
                #pragma unroll
                for (int t = 0; t < 16; ++t) g[t] = M[(16 * ka + t) * ES];
                fft16<-1>(g);
                #pragma unroll
                for (int kb = 0; kb < 16; ++kb) M[(16 * ka + kb) * ES] = g[kb];
            }
            __syncthreads();
        } else {
            // ---- step A: FFT16 over kb per block ka ----
            {
                int ka = tid >> 7, x = tid & 127;
                float2* M = F + x * LS;
                float2 g[16];
                #pragma unroll
                for (int kb = 0; kb < 16; ++kb) g[kb] = M[(16 * ka + kb) * ES];
                fft16<1>(g);
                #pragma unroll
                for (int t = 0; t < 16; ++t) {
                    float2 w = tw[t * ka];          // e^{+2pi i t ka/128}
                    float2 z = g[t];
                    M[(16 * ka + t) * ES] =
                        make_float2(z.x * w.x - z.y * w.y, z.x * w.y + z.y * w.x);
                }
            }
            __syncthreads();
            // ---- step B: FFT8 over ka per residue class t ----
            #pragma unroll
            for (int i = 0; i < 2; ++i) {
                int u = i * TT + tid;
                int t = u >> 7, x = u & 127;
                float2* M = F + x * LS;
                float2 f[8];
                #pragma unroll
                for (int ka = 0; ka < 8; ++ka) f[ka] = M[(16 * ka + t) * ES];
                fft8<1>(f);
                #pragma unroll
                for (int nh = 0; nh < 8; ++nh) M[(t + 16 * nh) * ES] = f[nh];
            }
            __syncthreads();
        }
    }
}

__device__ __forceinline__ float waveReduceSum(float v) {
    #pragma unroll
    for (int off = 32; off > 0; off >>= 1) v += __shfl_down(v, off, 64);
    return v;   // valid on lane 0
}

__device__ __forceinline__ void buildTw(float2* tw, int tid) {
    if (tid < 128) {
        float s, c;
        __sincosf((float)tid * 0.04908738521234052f, &s, &c);   // 2*pi/128
        tw[tid] = make_float2(c, s);
    }
}

// ---------- K1: Morlet filter bank (PERMUTED freq layout) + zero coeff accumulators ----------
__global__ void k_psi(float* __restrict__ psi, float* __restrict__ coeffs) {
    int blk = blockIdx.x, tid = threadIdx.x;
    if (blk == 16) {
        for (int i = tid; i < 64 * 11; i += 256) coeffs[i] = 0.f;
        return;
    }
    int j = blk >> 2, l = blk & 3;
    float k0    = 2.35619449019234493f / (float)(1 << j);   // 3*pi/4 / 2^j
    float sigma = 0.8f * (float)(1 << j);
    float s2    = sigma * sigma;
    float theta = 0.78539816339744831f * (float)l;          // pi*l/4
    float k0x = k0 * cosf(theta);
    float k0y = k0 * sinf(theta);
    float beta = expf(-0.5f * s2 * k0 * k0);
    const float FSTEP = 0.04908738521234052f;               // 2*pi/128
    float* dst = psi + (size_t)blk * NPIX;
    for (int i = tid; i < NPIX; i += 256) {
        int pr = i >> 7, pc = i & 127;
        int kr = (pr >> 4) + 8 * (pr & 15);   // position -> true frequency
        int kc = (pc >> 4) + 8 * (pc & 15);
        float fr = (float)(kr < 64 ? kr : kr - 128) * FSTEP;
        float fc = (float)(kc < 64 ? kc : kc - 128) * FSTEP;
        float dx = fr - k0x, dy = fc - k0y;
        float g1 = expf(-0.5f * s2 * (dx * dx + dy * dy));
        float g0 = expf(-0.5f * s2 * (fr * fr + fc * fc));
        dst[i] = g1 - beta * g0;
    }
}

// ---------- K2: i_hat = fft2(image) (permuted layout), s0 = mean(image) ----------
// LDS caps this at 1 block/CU -> 16 waves/CU -> 4 waves/EU. Tell the register
// allocator exactly that (VGPR cap 128); the default (64 VGPR / 8 waves-EU target)
// spilled uh/g to scratch: R2 showed 466+220 MB of HBM traffic = the whole runtime.
__global__ __launch_bounds__(TT, 4) void k_ihat(const float* __restrict__ img,
                                                float2* __restrict__ ihat,
                                                float* __restrict__ coeffs) {
    __shared__ float2 F[NN * SS];
    __shared__ float2 tw[128];
    int tid = threadIdx.x, b = blockIdx.x;
    buildTw(tw, tid);
    float acc = 0.f;
    #pragma unroll
    for (int k = 0; k < EPT; ++k) {
        int e = k * TT + tid;
        float v = img[(size_t)b * NPIX + e];
        acc += v;
        F[(e >> 7) * SS + (e & 127)] = make_float2(v, 0.f);
    }
    float ws = waveReduceSum(acc);
    if ((tid & 63) == 0) atomicAdd(&coeffs[b * 11 + 0], ws * (1.f / 16384.f));
    __syncthreads();
    fft2d<-1>(F, tw, tid);
    #pragma unroll
    for (int k = 0; k < EPT; ++k) {
        int e = k * TT + tid;
        ihat[(size_t)b * NPIX + e] = F[(e >> 7) * SS + (e & 127)];
    }
}

// ---------- K3: fused first+second order scattering per (b, j1, l1) ----------
__global__ __launch_bounds__(TT, 4) void k_scatter(const float2* __restrict__ ihat,
                                                   const float* __restrict__ psi,
                                                   float* __restrict__ coeffs) {
    __shared__ float2 F[NN * SS];
    __shared__ float2 tw[128];
    int tid = threadIdx.x;
    int x = blockIdx.x;
    int b = x & 63, l1 = (x >> 6) & 3, j1 = x >> 8;
    const float2* ih = ihat + (size_t)b * NPIX;
    const float*  p1 = psi + (size_t)(j1 * 4 + l1) * NPIX;
    buildTw(tw, tid);

    // load i_hat * psi_{j1,l1} (both in permuted freq layout)
    #pragma unroll
    for (int k = 0; k < EPT; ++k) {
        int e = k * TT + tid;
        float2 z = ih[e];
        float  p = p1[e];
        F[(e >> 7) * SS + (e & 127)] = make_float2(z.x * p, z.y * p);
    }
    __syncthreads();
    fft2d<1>(F, tw, tid);                  // inverse (unnormalized, x16384) -> spatial

    // u1 = |.| / 16384, write back as real field, accumulate s1
    float acc = 0.f;
    #pragma unroll
    for (int k = 0; k < EPT; ++k) {
        int e = k * TT + tid;
        int idx = (e >> 7) * SS + (e & 127);
        float2 z = F[idx];
        float m = sqrtf(z.x * z.x + z.y * z.y) * (1.f / 16384.f);
        acc += m;
        F[idx] = make_float2(m, 0.f);
    }
    float ws1 = waveReduceSum(acc);
    if ((tid & 63) == 0) atomicAdd(&coeffs[b * 11 + 1 + j1], ws1 * (1.f / 65536.f));
    __syncthreads();                       // mag writes visible before forward fft
    fft2d<-1>(F, tw, tid);                 // u1_hat, permuted freq layout

    // hold u1_hat in registers (32 VGPRs)
    float2 uh[EPT];
    #pragma unroll
    for (int k = 0; k < EPT; ++k) {
        int e = k * TT + tid;
        uh[k] = F[(e >> 7) * SS + (e & 127)];
    }

    const float inv2 = 2.3283064365386963e-10f;   // 1/(16384*16*16384) = 2^-32
    for (int j2 = j1 + 1; j2 < 4; ++j2) {
        int pair = (j1 == 0) ? (j2 - 1) : ((j1 == 1) ? (j2 + 1) : 5);
        for (int l2 = 0; l2 < 4; ++l2) {
            const float* p2 = psi + (size_t)(j2 * 4 + l2) * NPIX;
            __syncthreads();   // prior iteration's F reads (and uh capture) complete
            #pragma unroll
            for (int k = 0; k < EPT; ++k) {
                int e = k * TT + tid;
                float p = p2[e];
                F[(e >> 7) * SS + (e & 127)] = make_float2(uh[k].x * p, uh[k].y * p);
            }
            __syncthreads();
            fft2d<1>(F, tw, tid);
            float a2 = 0.f;
            #pragma unroll
            for (int k = 0; k < EPT; ++k) {
                int e = k * TT + tid;
                float2 z = F[(e >> 7) * SS + (e & 127)];
                a2 += sqrtf(z.x * z.x + z.y * z.y);
            }
            float ws2 = waveReduceSum(a2);
            if ((tid & 63) == 0) atomicAdd(&coeffs[b * 11 + 5 + pair], ws2 * inv2);
        }
    }
}

// ---------- K4: tiny MLP head ----------
__global__ void k_mlp(const float* __restrict__ coeffs,
                      const float* __restrict__ w1, const float* __restrict__ b1,
                      const float* __restrict__ w2, const float* __restrict__ b2,
                      float* __restrict__ out) {
    int b = threadIdx.x;
    if (b >= 64) return;
    float c[11];
    #pragma unroll
    for (int i = 0; i < 11; ++i) c[i] = coeffs[b * 11 + i];
    float h[4];
    #pragma unroll
    for (int k = 0; k < 4; ++k) {
        float s = b1[k];
        #pragma unroll
        for (int i = 0; i < 11; ++i) s += w1[k * 11 + i] * c[i];
        h[k] = fmaxf(s, 0.f);
    }
    #pragma unroll
    for (int o = 0; o < 10; ++o) {
        float s = b2[o];
        #pragma unroll
        for (int k = 0; k < 4; ++k) s += w2[o * 4 + k] * h[k];
        out[b * 10 + o] = 1.f / (1.f + expf(-s));
    }
}

extern "C" void kernel_launch(void* const* d_in, const int* in_sizes, int n_in,
                              void* d_out, int out_size, void* d_ws, size_t ws_size,
                              hipStream_t stream) {
    const float* img = (const float*)d_in[0];
    const float* w1  = (const float*)d_in[1];
    const float* b1  = (const float*)d_in[2];
    const float* w2  = (const float*)d_in[3];
    const float* b2  = (const float*)d_in[4];
    float* out = (float*)d_out;

    // workspace layout (floats): psi[16*16384] | ihat[64*16384 float2] | coeffs[64*11]
    float*  ws     = (float*)d_ws;
    float*  psi    = ws;
    float2* ihat   = (float2*)(ws + 16 * NPIX);
    float*  coeffs = ws + 16 * NPIX + 2 * 64 * NPIX;

    hipLaunchKernelGGL(k_psi,     dim3(17),   dim3(256), 0, stream, psi, coeffs);
    hipLaunchKernelGGL(k_ihat,    dim3(64),   dim3(TT),  0, stream, img, ihat, coeffs);
    hipLaunchKernelGGL(k_scatter, dim3(1024), dim3(TT),  0, stream, ihat, psi, coeffs);
    hipLaunchKernelGGL(k_mlp,     dim3(1),    dim3(64),  0, stream, coeffs, w1, b1, w2, b2, out);
}

// Round 4
// 536.923 us; speedup vs baseline: 1.3714x; 1.3714x over previous
//
#include <hip/hip_runtime.h>
#include <math.h>

#define NN   128
#define SS   129          // LDS row stride in float2 (ODD -> conflict-free lane stride)
#define TT   512          // threads per block for FFT kernels (512: compiler allocates
                          // ~112 VGPR with NO spill; TT=1024 spilled uh/g to scratch at
                          // 64 VGPR and 700 MB of HBM traffic -- R2/R3 evidence)
#define NPIX 16384        // 128*128
#define EPT  32           // NPIX / TT

// ---------- register FFTs (radix-2 DIF + final bit-reversal -> natural order) ----------
template<int SGN>
__device__ __forceinline__ void fft8(float2* f) {
    const float R = 0.70710678118654752f;
    const float WC[4] = {1.f, R, 0.f, -R};
    const float WS[4] = {0.f, R, 1.f, R};   // sin(2*pi*t/8)
    #pragma unroll
    for (int stage = 0; stage < 3; ++stage) {
        const int L = 8 >> stage, half = L >> 1, step = 1 << stage;
        #pragma unroll
        for (int base = 0; base < 8; base += L) {
            #pragma unroll
            for (int j = 0; j < half; ++j) {
                float2 u = f[base + j], v = f[base + half + j];
                f[base + j] = make_float2(u.x + v.x, u.y + v.y);
                float dx = u.x - v.x, dy = u.y - v.y;
                const int t = j * step;
                const float wr = WC[t];
                const float wi = (SGN > 0) ? WS[t] : -WS[t];
                f[base + half + j] = make_float2(dx * wr - dy * wi, dx * wi + dy * wr);
            }
        }
    }
    float2 tmp;
    tmp = f[1]; f[1] = f[4]; f[4] = tmp;
    tmp = f[3]; f[3] = f[6]; f[6] = tmp;
}

template<int SGN>
__device__ __forceinline__ void fft16(float2* f) {
    const float WC[8] = {1.f, 0.92387953251f, 0.70710678119f, 0.38268343236f,
                         0.f, -0.38268343236f, -0.70710678119f, -0.92387953251f};
    const float WS[8] = {0.f, 0.38268343236f, 0.70710678119f, 0.92387953251f,
                         1.f, 0.92387953251f, 0.70710678119f, 0.38268343236f};
    #pragma unroll
    for (int stage = 0; stage < 4; ++stage) {
        const int L = 16 >> stage, half = L >> 1, step = 1 << stage;
        #pragma unroll
        for (int base = 0; base < 16; base += L) {
            #pragma unroll
            for (int j = 0; j < half; ++j) {
                float2 u = f[base + j], v = f[base + half + j];
                f[base + j] = make_float2(u.x + v.x, u.y + v.y);
                float dx = u.x - v.x, dy = u.y - v.y;
                const int t = j * step;
                const float wr = WC[t];
                const float wi = (SGN > 0) ? WS[t] : -WS[t];
                f[base + half + j] = make_float2(dx * wr - dy * wi, dx * wi + dy * wr);
            }
        }
    }
    float2 tmp;
    tmp = f[1];  f[1]  = f[8];  f[8]  = tmp;
    tmp = f[2];  f[2]  = f[4];  f[4]  = tmp;
    tmp = f[3];  f[3]  = f[12]; f[12] = tmp;
    tmp = f[5];  f[5]  = f[10]; f[10] = tmp;
    tmp = f[7];  f[7]  = f[14]; f[14] = tmp;
    tmp = f[11]; f[11] = f[13]; f[13] = tmp;
}

// ---------- in-LDS 2D FFT, 128x128 ----------
// Frequency storage is BIT-PERMUTED along each axis: freq k = ka + 8*kb (ka<8, kb<16)
// lives at position p = 16*ka + kb.  psi / ihat are generated in the same layout.
// SGN=-1: forward (natural spatial in -> permuted freq out), unnormalized DFT.
// SGN=+1: inverse (permuted freq in -> natural spatial out), unnormalized (x16384).
// Residue-class-preserving writes: each unit reads/writes only its own (class, line)
// cells -> sweeps are hazard-free with no intra-sweep barriers; 4 barriers per 2D FFT.
// Lanes always vary the line index (row pass: lane stride SS=129 float2, odd; col pass:
// lane stride 1) -> every b64 LDS access sits at the wave64 structural minimum
// (4 lanes per bank-pair).  Verified R2/R3: SQ_LDS_BANK_CONFLICT == 0.
template<int SGN>
__device__ void fft2d(float2* __restrict__ F, const float2* __restrict__ tw, int tid) {
    #pragma unroll
    for (int pass = 0; pass < 2; ++pass) {
        const int ES = (pass == 0) ? 1 : SS;   // within-line element stride
        const int LS = (pass == 0) ? SS : 1;   // line stride
        if (SGN < 0) {
            // ---- step A: FFT8 over n1 per residue class t (16 classes x 128 lines) ----
            #pragma unroll
            for (int i = 0; i < 2048 / TT; ++i) {
                int u = i * TT + tid;
                int t = u >> 7, x = u & 127;
                float2* M = F + x * LS;
                float2 f[8];
                #pragma unroll
                for (int n1 = 0; n1 < 8; ++n1) f[n1] = M[(t + 16 * n1) * ES];
                fft8<-1>(f);
                #pragma unroll
                for (int ka = 0; ka < 8; ++ka) {
                    float2 w = tw[t * ka];          // e^{+2pi i t ka/128}; forward uses conj
                    float2 z = f[ka];
                    M[(t + 16 * ka) * ES] =
                        make_float2(z.x * w.x + z.y * w.y, z.y * w.x - z.x * w.y);
                }
            }
            __syncthreads();
            // ---- step B: FFT16 over t per block ka (8 classes x 128 lines) ----
            #pragma unroll
            for (int i = 0; i < 1024 / TT; ++i) {
                int u = i * TT + tid;
                int ka = u >> 7, x = u & 127;
                float2* M = F + x * LS;
                float2 g[16];
                #pragma unroll
                for (int t = 0; t < 16; ++t) g[t] = M[(16 * ka + t) * ES];
                fft16<-1>(g);
                #pragma unroll
                for (int kb = 0; kb < 16; ++kb) M[(16 * ka + kb) * ES] = g[kb];
            }
            __syncthreads();
        } else {
            // ---- step A: FFT16 over kb per block ka ----
            #pragma unroll
            for (int i = 0; i < 1024 / TT; ++i) {
                int u = i * TT + tid;
                int ka = u >> 7, x = u & 127;
                float2* M = F + x * LS;
                float2 g[16];
                #pragma unroll
                for (int kb = 0; kb < 16; ++kb) g[kb] = M[(16 * ka + kb) * ES];
                fft16<1>(g);
                #pragma unroll
                for (int t = 0; t < 16; ++t) {
                    float2 w = tw[t * ka];          // e^{+2pi i t ka/128}
                    float2 z = g[t];
                    M[(16 * ka + t) * ES] =
                        make_float2(z.x * w.x - z.y * w.y, z.x * w.y + z.y * w.x);
                }
            }
            __syncthreads();
            // ---- step B: FFT8 over ka per residue class t ----
            #pragma unroll
            for (int i = 0; i < 2048 / TT; ++i) {
                int u = i * TT + tid;
                int t = u >> 7, x = u & 127;
                float2* M = F + x * LS;
                float2 f[8];
                #pragma unroll
                for (int ka = 0; ka < 8; ++ka) f[ka] = M[(16 * ka + t) * ES];
                fft8<1>(f);
                #pragma unroll
                for (int nh = 0; nh < 8; ++nh) M[(t + 16 * nh) * ES] = f[nh];
            }
            __syncthreads();
        }
    }
}

__device__ __forceinline__ float waveReduceSum(float v) {
    #pragma unroll
    for (int off = 32; off > 0; off >>= 1) v += __shfl_down(v, off, 64);
    return v;   // valid on lane 0
}

__device__ __forceinline__ void buildTw(float2* tw, int tid) {
    if (tid < 128) {
        float s, c;
        __sincosf((float)tid * 0.04908738521234052f, &s, &c);   // 2*pi/128
        tw[tid] = make_float2(c, s);
    }
}

// ---------- K1: Morlet filter bank (PERMUTED freq layout) + zero coeff accumulators ----------
__global__ void k_psi(float* __restrict__ psi, float* __restrict__ coeffs) {
    int blk = blockIdx.x, tid = threadIdx.x;
    if (blk == 16) {
        for (int i = tid; i < 64 * 11; i += 256) coeffs[i] = 0.f;
        return;
    }
    int j = blk >> 2, l = blk & 3;
    float k0    = 2.35619449019234493f / (float)(1 << j);   // 3*pi/4 / 2^j
    float sigma = 0.8f * (float)(1 << j);
    float s2    = sigma * sigma;
    float theta = 0.78539816339744831f * (float)l;          // pi*l/4
    float k0x = k0 * cosf(theta);
    float k0y = k0 * sinf(theta);
    float beta = expf(-0.5f * s2 * k0 * k0);
    const float FSTEP = 0.04908738521234052f;               // 2*pi/128
    float* dst = psi + (size_t)blk * NPIX;
    for (int i = tid; i < NPIX; i += 256) {
        int pr = i >> 7, pc = i & 127;
        int kr = (pr >> 4) + 8 * (pr & 15);   // position -> true frequency
        int kc = (pc >> 4) + 8 * (pc & 15);
        float fr = (float)(kr < 64 ? kr : kr - 128) * FSTEP;
        float fc = (float)(kc < 64 ? kc : kc - 128) * FSTEP;
        float dx = fr - k0x, dy = fc - k0y;
        float g1 = expf(-0.5f * s2 * (dx * dx + dy * dy));
        float g0 = expf(-0.5f * s2 * (fr * fr + fc * fc));
        dst[i] = g1 - beta * g0;
    }
}

// ---------- K2: i_hat = fft2(image) (permuted layout), s0 = mean(image) ----------
// LDS (132 KB) caps at 1 block/CU = 8 waves/CU = 2 waves/EU.  Pin the allocator to
// exactly that (budget 512/2 = 256 VGPR) so it can never choose spill-for-occupancy:
// R2/R3 showed the TT=1024 default heuristic spilled uh/g (466+220 MB HBM traffic).
__global__ __attribute__((amdgpu_flat_work_group_size(TT, TT), amdgpu_waves_per_eu(2, 2)))
void k_ihat(const float* __restrict__ img,
            float2* __restrict__ ihat,
            float* __restrict__ coeffs) {
    __shared__ float2 F[NN * SS];
    __shared__ float2 tw[128];
    int tid = threadIdx.x, b = blockIdx.x;
    buildTw(tw, tid);
    float acc = 0.f;
    #pragma unroll
    for (int k = 0; k < EPT; ++k) {
        int e = k * TT + tid;
        float v = img[(size_t)b * NPIX + e];
        acc += v;
        F[(e >> 7) * SS + (e & 127)] = make_float2(v, 0.f);
    }
    float ws = waveReduceSum(acc);
    if ((tid & 63) == 0) atomicAdd(&coeffs[b * 11 + 0], ws * (1.f / 16384.f));
    __syncthreads();
    fft2d<-1>(F, tw, tid);
    #pragma unroll
    for (int k = 0; k < EPT; ++k) {
        int e = k * TT + tid;
        ihat[(size_t)b * NPIX + e] = F[(e >> 7) * SS + (e & 127)];
    }
}

// ---------- K3: fused first+second order scattering per (b, j1, l1) ----------
__global__ __attribute__((amdgpu_flat_work_group_size(TT, TT), amdgpu_waves_per_eu(2, 2)))
void k_scatter(const float2* __restrict__ ihat,
               const float* __restrict__ psi,
               float* __restrict__ coeffs) {
    __shared__ float2 F[NN * SS];
    __shared__ float2 tw[128];
    int tid = threadIdx.x;
    int x = blockIdx.x;
    int b = x & 63, l1 = (x >> 6) & 3, j1 = x >> 8;
    const float2* ih = ihat + (size_t)b * NPIX;
    const float*  p1 = psi + (size_t)(j1 * 4 + l1) * NPIX;
    buildTw(tw, tid);

    // load i_hat * psi_{j1,l1} (both in permuted freq layout)
    #pragma unroll
    for (int k = 0; k < EPT; ++k) {
        int e = k * TT + tid;
        float2 z = ih[e];
        float  p = p1[e];
        F[(e >> 7) * SS + (e & 127)] = make_float2(z.x * p, z.y * p);
    }
    __syncthreads();
    fft2d<1>(F, tw, tid);                  // inverse (unnormalized, x16384) -> spatial

    // u1 = |.| / 16384, write back as real field, accumulate s1
    float acc = 0.f;
    #pragma unroll
    for (int k = 0; k < EPT; ++k) {
        int e = k * TT + tid;
        int idx = (e >> 7) * SS + (e & 127);
        float2 z = F[idx];
        float m = sqrtf(z.x * z.x + z.y * z.y) * (1.f / 16384.f);
        acc += m;
        F[idx] = make_float2(m, 0.f);
    }
    float ws1 = waveReduceSum(acc);
    if ((tid & 63) == 0) atomicAdd(&coeffs[b * 11 + 1 + j1], ws1 * (1.f / 65536.f));
    __syncthreads();                       // mag writes visible before forward fft
    fft2d<-1>(F, tw, tid);                 // u1_hat, permuted freq layout

    // hold u1_hat in registers (64 VGPRs)
    float2 uh[EPT];
    #pragma unroll
    for (int k = 0; k < EPT; ++k) {
        int e = k * TT + tid;
        uh[k] = F[(e >> 7) * SS + (e & 127)];
    }

    const float inv2 = 2.3283064365386963e-10f;   // 1/(16384*16*16384) = 2^-32
    for (int j2 = j1 + 1; j2 < 4; ++j2) {
        int pair = (j1 == 0) ? (j2 - 1) : ((j1 == 1) ? (j2 + 1) : 5);
        for (int l2 = 0; l2 < 4; ++l2) {
            const float* p2 = psi + (size_t)(j2 * 4 + l2) * NPIX;
            __syncthreads();   // prior iteration's F reads (and uh capture) complete
            #pragma unroll
            for (int k = 0; k < EPT; ++k) {
                int e = k * TT + tid;
                float p = p2[e];
                F[(e >> 7) * SS + (e & 127)] = make_float2(uh[k].x * p, uh[k].y * p);
            }
            __syncthreads();
            fft2d<1>(F, tw, tid);
            float a2 = 0.f;
            #pragma unroll
            for (int k = 0; k < EPT; ++k) {
                int e = k * TT + tid;
                float2 z = F[(e >> 7) * SS + (e & 127)];
                a2 += sqrtf(z.x * z.x + z.y * z.y);
            }
            float ws2 = waveReduceSum(a2);
            if ((tid & 63) == 0) atomicAdd(&coeffs[b * 11 + 5 + pair], ws2 * inv2);
        }
    }
}

// ---------- K4: tiny MLP head ----------
__global__ void k_mlp(const float* __restrict__ coeffs,
                      const float* __restrict__ w1, const float* __restrict__ b1,
                      const float* __restrict__ w2, const float* __restrict__ b2,
                      float* __restrict__ out) {
    int b = threadIdx.x;
    if (b >= 64) return;
    float c[11];
    #pragma unroll
    for (int i = 0; i < 11; ++i) c[i] = coeffs[b * 11 + i];
    float h[4];
    #pragma unroll
    for (int k = 0; k < 4; ++k) {
        float s = b1[k];
        #pragma unroll
        for (int i = 0; i < 11; ++i) s += w1[k * 11 + i] * c[i];
        h[k] = fmaxf(s, 0.f);
    }
    #pragma unroll
    for (int o = 0; o < 10; ++o) {
        float s = b2[o];
        #pragma unroll
        for (int k = 0; k < 4; ++k) s += w2[o * 4 + k] * h[k];
        out[b * 10 + o] = 1.f / (1.f + expf(-s));
    }
}

extern "C" void kernel_launch(void* const* d_in, const int* in_sizes, int n_in,
                              void* d_out, int out_size, void* d_ws, size_t ws_size,
                              hipStream_t stream) {
    const float* img = (const float*)d_in[0];
    const float* w1  = (const float*)d_in[1];
    const float* b1  = (const float*)d_in[2];
    const float* w2  = (const float*)d_in[3];
    const float* b2  = (const float*)d_in[4];
    float* out = (float*)d_out;

    // workspace layout (floats): psi[16*16384] | ihat[64*16384 float2] | coeffs[64*11]
    float*  ws     = (float*)d_ws;
    float*  psi    = ws;
    float2* ihat   = (float2*)(ws + 16 * NPIX);
    float*  coeffs = ws + 16 * NPIX + 2 * 64 * NPIX;

    hipLaunchKernelGGL(k_psi,     dim3(17),   dim3(256), 0, stream, psi, coeffs);
    hipLaunchKernelGGL(k_ihat,    dim3(64),   dim3(TT),  0, stream, img, ihat, coeffs);
    hipLaunchKernelGGL(k_scatter, dim3(1024), dim3(TT),  0, stream, ihat, psi, coeffs);
    hipLaunchKernelGGL(k_mlp,     dim3(1),    dim3(64),  0, stream, coeffs, w1, b1, w2, b2, out);
}